// Round 4
// baseline (111.259 us; speedup 1.0000x reference)
//
#include <hip/hip_runtime.h>
#include <hip/hip_fp16.h>

// Warp: trilinear grid_sample, padding_mode='zeros', align_corners=true.
// image: (B=2, C=1, H=128, W=128, D=128) fp32
// ddf:   (B=2, 3, H, W, D) fp32 voxel displacements; out: (B,1,H,W,D) fp32
//
// R15: rolling-x column. Each block computes TWO x-adjacent 16^3 tiles,
// holding a circular 32-x-plane fp16 window in LDS (slot = x & 31).
//  - shared x-halo staged once: amplification 8x -> 6x (-25% staging
//    loads / cvt+pack / ds_write)
//  - step-2 staging loads issued right AFTER the first barrier, consumed
//    after the post-compute-1 barrier: HBM latency hides under tile-1
//    compute (T14 arranged around __syncthreads' mandatory vmcnt(0) drain,
//    which killed the R13 attempt at pre-barrier prefetch).
//  - circularity along x only: the z-pair ds_read2+v_alignbit tap path is
//    unchanged; x0 and x0+1 rows are independently addressed via (x&31),
//    so no wrap hazard exists.
// Grid: 512 blocks = exactly 2/CU (32 waves/CU). XCD swizzle: XCD k owns one
// contiguous x-column slab (48 planes ~3MB, fits 4MB L2).
// Keep: R12 18-cell row padding, R14 setprio(1) around compute phases.
// VGPR must stay <=64 for 8 waves/SIMD: ddf2 is loaded late (after the
// post-compute-1 barrier) to cap live registers during compute-1.

constexpr int H = 128, W = 128, D = 128;
constexpr int N = H * W * D;      // 2^21
constexpr int B = 2;
constexpr int RCELL = 18;         // padded cells (half2) per row (16 data + 2 pad)
constexpr int RHALF = RCELL * 2;  // halfs per row = 36
constexpr int RN = 1024 * RHALF;  // 1024 rows (32 x-slots * 32 y) = 72 KB

typedef float fvec4 __attribute__((ext_vector_type(4)));
typedef unsigned u2v __attribute__((ext_vector_type(2), aligned(4)));
typedef unsigned u2v8 __attribute__((ext_vector_type(2), aligned(8)));

__global__ __launch_bounds__(1024, 8) void warp_tile_kernel(
    const float* __restrict__ image,
    const float* __restrict__ ddf,
    float* __restrict__ out)
{
    __shared__ __half tile[RN];   // 72 KB -> 2 blocks/CU

    // 512 blocks: XCD k (bid&7) gets contiguous column range [k*64,(k+1)*64).
    // Column T: b = T>>8; t3 = T&255: xcol(2b) | ty(3b) | tz(3b).
    int bid = blockIdx.x;
    int T   = (bid & 7) * 64 + (bid >> 3);
    int b   = T >> 8;
    int t3  = T & 255;
    int xcol = t3 >> 6;               // 0..3 -> tiles at x = 32*xcol, +16
    int ty0 = ((t3 >> 3) & 7) << 4;
    int tz0 = (t3 & 7) << 4;
    int tx1 = xcol << 5;
    int ox1 = tx1 - 8;                // window-1 low x (slot = x & 31)
    int oy  = ty0 - 8, oz = tz0 - 8;

    const float* img  = image + ((size_t)b << 21);
    float*       outb = out   + ((size_t)b << 21);
    const float* ddfb = ddf + (size_t)b * 3 * N;
    int t = threadIdx.x;          // 0..1023

    // ---- thread -> 4 consecutive z voxels (per tile) ----
    int zq = (t & 3) << 2;        // 0,4,8,12
    int ly = (t >> 2) & 15;
    int lx = t >> 6;
    int vy = ty0 + ly, vz = tz0 + zq;
    int vx1 = tx1 + lx;
    int lin1 = (vx1 << 14) + (vy << 7) + vz;     // 16B aligned

    const unsigned int* cells = (const unsigned int*)tile;
    unsigned short* tp = (unsigned short*)tile;

    // ---- shared compute+store for one tile (inlined twice) ----
    auto compute_tile = [&](int vx, int ox, const fvec4& dX, const fvec4& dY,
                            const fvec4& dZ, int lin) {
        float dxp[4] = {dX.x, dX.y, dX.z, dX.w};
        float dyp[4] = {dY.x, dY.y, dY.z, dY.w};
        float dzp[4] = {dZ.x, dZ.y, dZ.z, dZ.w};
        float res[4];
        __builtin_amdgcn_s_setprio(1);
#pragma unroll
        for (int i = 0; i < 4; ++i) {
            float x = (float)vx + dxp[i];
            float y = (float)vy + dyp[i];
            float z = (float)(vz + i) + dzp[i];

            float xf = floorf(x), yf = floorf(y), zf = floorf(z);
            float fx = x - xf, fy = y - yf, fz = z - zf;
            int x0 = (int)xf, y0 = (int)yf, z0 = (int)zf;
            int rx = x0 - ox, ry = y0 - oy, rz = z0 - oz;

            float acc;
            if ((unsigned)rx <= 30u && (unsigned)ry <= 30u && (unsigned)rz <= 30u) {
                // fast path: staged zeros implement zero-padding exactly.
                // rows addressed by physical slot (x&31): circular window.
                int r0 = ((x0 & 31) << 5) + ry;
                int r1 = (((x0 + 1) & 31) << 5) + ry;
                int czi = rz >> 1;
                int sh  = (rz & 1) << 4;
                int c00 = r0 * RCELL + czi;
                int c10 = r1 * RCELL + czi;
                u2v q00 = *(const u2v*)(cells + c00);
                u2v q01 = *(const u2v*)(cells + c00 + RCELL);
                u2v q10 = *(const u2v*)(cells + c10);
                u2v q11 = *(const u2v*)(cells + c10 + RCELL);

                float az0 = 1.f - fz;
                float zz[4];
                unsigned los[4] = {q00.x, q01.x, q10.x, q11.x};
                unsigned his[4] = {q00.y, q01.y, q10.y, q11.y};
#pragma unroll
                for (int p2 = 0; p2 < 4; ++p2) {
                    unsigned pr = __builtin_amdgcn_alignbit(his[p2], los[p2],
                                                            (unsigned)sh);
                    __half2 hp = *(__half2*)&pr;
                    float2 f2 = __half22float2(hp);
                    zz[p2] = az0 * f2.x + fz * f2.y;
                }
                float ay0 = 1.f - fy;
                acc = (1.f - fx) * (ay0 * zz[0] + fy * zz[1]) +
                      fx         * (ay0 * zz[2] + fy * zz[3]);
            } else {
                // rare: exact fp32 global gather with zero-padding.
                int x1 = x0 + 1, y1 = y0 + 1, z1 = z0 + 1;
                bool vx0 = (unsigned)x0 < (unsigned)H;
                bool vx1b = (unsigned)x1 < (unsigned)H;
                bool vy0 = (unsigned)y0 < (unsigned)W;
                bool vy1 = (unsigned)y1 < (unsigned)W;
                bool vz0 = (unsigned)z0 < (unsigned)D;
                bool vz1 = (unsigned)z1 < (unsigned)D;
                float ax0 = vx0 ? (1.0f - fx) : 0.0f;
                float ax1 = vx1b ? fx         : 0.0f;
                float ay0 = vy0 ? (1.0f - fy) : 0.0f;
                float ay1 = vy1 ? fy          : 0.0f;
                float az0 = vz0 ? (1.0f - fz) : 0.0f;
                float az1 = vz1 ? fz          : 0.0f;
                int cx0 = vx0 ? x0 : 0;
                int cx1 = vx1b ? x1 : 0;
                int cy0 = vy0 ? y0 : 0;
                int cy1 = vy1 ? y1 : 0;
                int cz0 = vz0 ? z0 : 0;
                int cz1 = vz1 ? z1 : 0;
                int rx0 = cx0 << 14, rx1i = cx1 << 14;
                int ry0 = cy0 << 7,  ry1 = cy1 << 7;
                float v000 = img[rx0 + ry0 + cz0];
                float v001 = img[rx0 + ry0 + cz1];
                float v010 = img[rx0 + ry1 + cz0];
                float v011 = img[rx0 + ry1 + cz1];
                float v100 = img[rx1i + ry0 + cz0];
                float v101 = img[rx1i + ry0 + cz1];
                float v110 = img[rx1i + ry1 + cz0];
                float v111 = img[rx1i + ry1 + cz1];
                acc = ax0 * (ay0 * (az0 * v000 + az1 * v001) +
                             ay1 * (az0 * v010 + az1 * v011)) +
                      ax1 * (ay0 * (az0 * v100 + az1 * v101) +
                             ay1 * (az0 * v110 + az1 * v111));
            }
            res[i] = acc;
        }
        __builtin_amdgcn_s_setprio(0);
        fvec4 r4 = {res[0], res[1], res[2], res[3]};
        __builtin_nontemporal_store(r4, (fvec4*)(outb + lin));
    };

    // ---- stage window 1: x-planes [ox1, ox1+32), slot = x & 31 ----
    // 4096 8-float chunks; chunk s: plane = (s>>2)>>5, y = (s>>2)&31,
    // zo = (s&3)*8. oz = 0 mod 8 -> chunk fully inside or fully outside.
    {
        fvec4 sa[4], sb[4];
        int srow[4], zos[4];
#pragma unroll
        for (int c = 0; c < 4; ++c) {
            int s   = c * 1024 + t;
            int row = s >> 2;
            int p   = row >> 5;
            int yy  = row & 31;
            int zo  = (s & 3) << 3;
            int gx = ox1 + p;
            int gy = oy + yy;
            int gz = oz + zo;
            srow[c] = ((gx & 31) << 5) + yy;
            zos[c]  = zo;
            bool ok = ((unsigned)gx < 128u) & ((unsigned)gy < 128u) & ((unsigned)gz < 121u);
            const float* pp = img + (gx << 14) + (gy << 7) + gz;
            fvec4 z4 = {0.f, 0.f, 0.f, 0.f};
            sa[c] = ok ? *(const fvec4*)pp       : z4;
            sb[c] = ok ? *(const fvec4*)(pp + 4) : z4;
        }
        // ddf for tile 1 (drained at the barrier with everything else)
        fvec4 dxa = *(const fvec4*)(ddfb + lin1);
        fvec4 dya = *(const fvec4*)(ddfb + lin1 + N);
        fvec4 dza = *(const fvec4*)(ddfb + lin1 + 2 * N);

#pragma unroll
        for (int c = 0; c < 4; ++c) {
            __half2 h0 = __floats2half2_rn(sa[c].x, sa[c].y);
            __half2 h1 = __floats2half2_rn(sa[c].z, sa[c].w);
            __half2 h2 = __floats2half2_rn(sb[c].x, sb[c].y);
            __half2 h3 = __floats2half2_rn(sb[c].z, sb[c].w);
            u2v8 w0, w1;
            w0.x = *(unsigned int*)&h0;
            w0.y = *(unsigned int*)&h1;
            w1.x = *(unsigned int*)&h2;
            w1.y = *(unsigned int*)&h3;
            unsigned short* dst = tp + srow[c] * RHALF + zos[c];
            *(u2v8*)dst       = w0;   // ds_write_b64 (8B aligned)
            *(u2v8*)(dst + 4) = w1;
        }
        __syncthreads();

        // ---- issue stage-2 loads NOW: x-planes [tx1+24, tx1+40) ----
        // In flight during compute-1; drained by the post-compute barrier.
        fvec4 s2a[2], s2b[2];
        int srow2[2], zos2[2];
#pragma unroll
        for (int c = 0; c < 2; ++c) {
            int s   = c * 1024 + t;
            int row = s >> 2;         // 0..511: plane(4b) | y(5b)
            int p   = row >> 5;       // 0..15
            int yy  = row & 31;
            int zo  = (s & 3) << 3;
            int gx = tx1 + 24 + p;
            int gy = oy + yy;
            int gz = oz + zo;
            srow2[c] = ((gx & 31) << 5) + yy;
            zos2[c]  = zo;
            bool ok = ((unsigned)gx < 128u) & ((unsigned)gy < 128u) & ((unsigned)gz < 121u);
            const float* pp = img + (gx << 14) + (gy << 7) + gz;
            fvec4 z4 = {0.f, 0.f, 0.f, 0.f};
            s2a[c] = ok ? *(const fvec4*)pp       : z4;
            s2b[c] = ok ? *(const fvec4*)(pp + 4) : z4;
        }

        // ---- compute tile 1 (window x in [ox1, ox1+32)) ----
        compute_tile(vx1, ox1, dxa, dya, dza, lin1);

        __syncthreads();   // window-1 reads done; stage-2 loads drained

        // ddf for tile 2 (issued before pack/write-2; latency hidden under
        // the write+barrier; loaded late to cap VGPRs during compute-1)
        int lin2 = lin1 + (16 << 14);
        fvec4 dxb = *(const fvec4*)(ddfb + lin2);
        fvec4 dyb = *(const fvec4*)(ddfb + lin2 + N);
        fvec4 dzb = *(const fvec4*)(ddfb + lin2 + 2 * N);

#pragma unroll
        for (int c = 0; c < 2; ++c) {
            __half2 h0 = __floats2half2_rn(s2a[c].x, s2a[c].y);
            __half2 h1 = __floats2half2_rn(s2a[c].z, s2a[c].w);
            __half2 h2 = __floats2half2_rn(s2b[c].x, s2b[c].y);
            __half2 h3 = __floats2half2_rn(s2b[c].z, s2b[c].w);
            u2v8 w0, w1;
            w0.x = *(unsigned int*)&h0;
            w0.y = *(unsigned int*)&h1;
            w1.x = *(unsigned int*)&h2;
            w1.y = *(unsigned int*)&h3;
            unsigned short* dst = tp + srow2[c] * RHALF + zos2[c];
            *(u2v8*)dst       = w0;
            *(u2v8*)(dst + 4) = w1;
        }
        __syncthreads();

        // ---- compute tile 2 (window x in [ox1+16, ox1+48)) ----
        compute_tile(vx1 + 16, ox1 + 16, dxb, dyb, dzb, lin2);
    }
}

extern "C" void kernel_launch(void* const* d_in, const int* in_sizes, int n_in,
                              void* d_out, int out_size, void* d_ws, size_t ws_size,
                              hipStream_t stream) {
    const float* image = (const float*)d_in[0];
    const float* ddf   = (const float*)d_in[1];
    float* out = (float*)d_out;

    warp_tile_kernel<<<B * 256, 1024, 0, stream>>>(image, ddf, out);
}

// Round 5
// 111.131 us; speedup vs baseline: 1.0011x; 1.0011x over previous
//
#include <hip/hip_runtime.h>
#include <hip/hip_fp16.h>

// Warp: trilinear grid_sample, padding_mode='zeros', align_corners=true.
// image: (B=2, C=1, H=128, W=128, D=128) fp32
// ddf:   (B=2, 3, H, W, D) fp32 voxel displacements; out: (B,1,H,W,D) fp32
//
// R16 = R14 structure (best, 102.5us) with two micro-fixes:
// (1) ddf loads moved AFTER __syncthreads: pre-barrier vmcnt(0) no longer
//     drains 48B/lane of full-HBM ddf latency while all 16 waves are
//     barrier-blocked (uncoverable by the block's own waves); the stall
//     moves to the compute phase where waves stagger individually and the
//     stage path waits only on L2-warm slab loads. (R13's reorder was a
//     no-op because it stayed on ONE side of the barrier; this crosses it.)
// (2) revert R12's 18-cell LDS padding (read-side conflicts proven hidden):
//     16-cell rows restore 16B-aligned ds_write_b128 staging (4 vs 8
//     ds_writes/thread).
// Kept: 1024 independent one-shot blocks (R15's 2-tile rolling column with
// extra barriers regressed 8.8us), XCD slab swizzle, setprio(1) compute
// phase, fp16 tile, z-pair uint2 taps + v_alignbit, rare-path fp32 gather.

constexpr int H = 128, W = 128, D = 128;
constexpr int N = H * W * D;      // 2^21
constexpr int B = 2;
constexpr int HA = 8;             // halo per side
constexpr int RS = 32;            // region edge
constexpr int RN = RS * RS * RS;  // 32768 fp16 = 64 KB

typedef float fvec4 __attribute__((ext_vector_type(4)));
typedef unsigned u2v __attribute__((ext_vector_type(2), aligned(4)));

__global__ __launch_bounds__(1024, 8) void warp_tile_kernel(
    const float* __restrict__ image,
    const float* __restrict__ ddf,
    float* __restrict__ out)
{
    __shared__ __half tile[RN];   // 64 KB -> 2 blocks/CU

    // XCD slab swizzle: blocks dispatch round-robin over 8 XCDs; give XCD k
    // the contiguous tile range [k*128, (k+1)*128) (= 2 x-slabs, ~2MB image
    // region + halos -> fits that XCD's 4MB L2).
    int bid = blockIdx.x;
    int T   = (bid & 7) * 128 + (bid >> 3);
    int b  = T >> 9;              // 512 tiles per batch
    int t3 = T & 511;
    int tx0 = ((t3 >> 6) & 7) << 4;
    int ty0 = ((t3 >> 3) & 7) << 4;
    int tz0 = (t3 & 7) << 4;
    int ox = tx0 - HA, oy = ty0 - HA, oz = tz0 - HA;

    const float* img = image + ((size_t)b << 21);
    int t = threadIdx.x;          // 0..1023

    // ---- thread -> 4 consecutive z voxels ----
    int zq = (t & 3) << 2;        // 0,4,8,12
    int ly = (t >> 2) & 15;
    int lx = t >> 6;
    int vx = tx0 + lx, vy = ty0 + ly, vz = tz0 + zq;
    int lin0 = (vx << 14) + (vy << 7) + vz;      // 16B aligned

    // ---- stage 32^3 region as fp16 (zeros outside volume) ----
    // 4096 32-byte slots; slot s: row = s>>2 (rx*32+ry), zo = (s&3)*8.
    // oz = 0 mod 8 -> each 8-float chunk fully inside or fully outside.
    fvec4 sa[4], sb[4];
    int rows[4], zos[4];
#pragma unroll
    for (int c = 0; c < 4; ++c) {
        int s   = c * 1024 + t;
        int row = s >> 2;
        int zo  = (s & 3) << 3;
        rows[c] = row; zos[c] = zo;
        int gx = ox + (row >> 5);
        int gy = oy + (row & 31);
        int gz = oz + zo;
        bool ok = ((unsigned)gx < 128u) & ((unsigned)gy < 128u) & ((unsigned)gz < 121u);
        const float* p = img + (gx << 14) + (gy << 7) + gz;
        fvec4 z4 = {0.f, 0.f, 0.f, 0.f};
        sa[c] = ok ? *(const fvec4*)p       : z4;
        sb[c] = ok ? *(const fvec4*)(p + 4) : z4;
    }
    unsigned short* tp = (unsigned short*)tile;
#pragma unroll
    for (int c = 0; c < 4; ++c) {
        __half2 h0 = __floats2half2_rn(sa[c].x, sa[c].y);
        __half2 h1 = __floats2half2_rn(sa[c].z, sa[c].w);
        __half2 h2 = __floats2half2_rn(sb[c].x, sb[c].y);
        __half2 h3 = __floats2half2_rn(sb[c].z, sb[c].w);
        uint4 pk;
        pk.x = *(unsigned int*)&h0;
        pk.y = *(unsigned int*)&h1;
        pk.z = *(unsigned int*)&h2;
        pk.w = *(unsigned int*)&h3;
        *(uint4*)(tp + rows[c] * 32 + zos[c]) = pk;   // ds_write_b128
    }
    __syncthreads();

    // ddf loads AFTER the barrier: their HBM latency lands in the compute
    // phase (per-wave staggered, TLP-covered) instead of the barrier drain.
    const float* ddfb = ddf + (size_t)b * 3 * N;
    fvec4 dx4 = *(const fvec4*)(ddfb + lin0);
    fvec4 dy4 = *(const fvec4*)(ddfb + lin0 + N);
    fvec4 dz4 = *(const fvec4*)(ddfb + lin0 + 2 * N);

    // Compute phase: boost issue priority (T5, independent-block regime).
    __builtin_amdgcn_s_setprio(1);

    // ---- compute 4 outputs (consecutive z), one float4 store ----
    float* outb = out + ((size_t)b << 21);
    const unsigned int* cells = (const unsigned int*)tile;   // half2 cells, 4B
    float dxp[4] = {dx4.x, dx4.y, dx4.z, dx4.w};
    float dyp[4] = {dy4.x, dy4.y, dy4.z, dy4.w};
    float dzp[4] = {dz4.x, dz4.y, dz4.z, dz4.w};
    float res[4];

#pragma unroll
    for (int i = 0; i < 4; ++i) {
        float x = (float)vx + dxp[i];
        float y = (float)vy + dyp[i];
        float z = (float)(vz + i) + dzp[i];

        float xf = floorf(x), yf = floorf(y), zf = floorf(z);
        float fx = x - xf, fy = y - yf, fz = z - zf;
        int x0 = (int)xf, y0 = (int)yf, z0 = (int)zf;
        int rx = x0 - ox, ry = y0 - oy, rz = z0 - oz;

        float acc;
        if ((unsigned)rx <= 30u && (unsigned)ry <= 30u && (unsigned)rz <= 30u) {
            // fast path: staged zeros implement zero-padding exactly.
            // z-pair (rz, rz+1) in cells c,c+1 (4B-aligned uint2 ->
            // ds_read2_b32; straddle resolved with v_alignbit).
            int rowc = ((rx << 5) + ry) << 4;   // row * 16 cells
            int c  = rowc + (rz >> 1);
            int sh = (rz & 1) << 4;
            u2v q00 = *(const u2v*)(cells + c);
            u2v q01 = *(const u2v*)(cells + c + 16);
            u2v q10 = *(const u2v*)(cells + c + 512);
            u2v q11 = *(const u2v*)(cells + c + 528);

            float az0 = 1.f - fz;
            float zz[4];
            unsigned los[4] = {q00.x, q01.x, q10.x, q11.x};
            unsigned his[4] = {q00.y, q01.y, q10.y, q11.y};
#pragma unroll
            for (int p2 = 0; p2 < 4; ++p2) {
                unsigned pr = __builtin_amdgcn_alignbit(his[p2], los[p2],
                                                        (unsigned)sh);
                __half2 hp = *(__half2*)&pr;
                float2 f2 = __half22float2(hp);
                zz[p2] = az0 * f2.x + fz * f2.y;
            }
            float ay0 = 1.f - fy;
            acc = (1.f - fx) * (ay0 * zz[0] + fy * zz[1]) +
                  fx         * (ay0 * zz[2] + fy * zz[3]);
        } else {
            // rare (~0.3%/lane): exact fp32 global gather with zero-padding.
            int x1 = x0 + 1, y1 = y0 + 1, z1 = z0 + 1;
            bool vx0 = (unsigned)x0 < (unsigned)H;
            bool vx1 = (unsigned)x1 < (unsigned)H;
            bool vy0 = (unsigned)y0 < (unsigned)W;
            bool vy1 = (unsigned)y1 < (unsigned)W;
            bool vz0 = (unsigned)z0 < (unsigned)D;
            bool vz1 = (unsigned)z1 < (unsigned)D;
            float ax0 = vx0 ? (1.0f - fx) : 0.0f;
            float ax1 = vx1 ? fx          : 0.0f;
            float ay0 = vy0 ? (1.0f - fy) : 0.0f;
            float ay1 = vy1 ? fy          : 0.0f;
            float az0 = vz0 ? (1.0f - fz) : 0.0f;
            float az1 = vz1 ? fz          : 0.0f;
            int cx0 = vx0 ? x0 : 0;
            int cx1 = vx1 ? x1 : 0;
            int cy0 = vy0 ? y0 : 0;
            int cy1 = vy1 ? y1 : 0;
            int cz0 = vz0 ? z0 : 0;
            int cz1 = vz1 ? z1 : 0;
            int rx0 = cx0 << 14, rx1 = cx1 << 14;
            int ry0 = cy0 << 7,  ry1 = cy1 << 7;
            float v000 = img[rx0 + ry0 + cz0];
            float v001 = img[rx0 + ry0 + cz1];
            float v010 = img[rx0 + ry1 + cz0];
            float v011 = img[rx0 + ry1 + cz1];
            float v100 = img[rx1 + ry0 + cz0];
            float v101 = img[rx1 + ry0 + cz1];
            float v110 = img[rx1 + ry1 + cz0];
            float v111 = img[rx1 + ry1 + cz1];
            acc = ax0 * (ay0 * (az0 * v000 + az1 * v001) +
                         ay1 * (az0 * v010 + az1 * v011)) +
                  ax1 * (ay0 * (az0 * v100 + az1 * v101) +
                         ay1 * (az0 * v110 + az1 * v111));
        }
        res[i] = acc;
    }
    __builtin_amdgcn_s_setprio(0);
    fvec4 r4 = {res[0], res[1], res[2], res[3]};
    __builtin_nontemporal_store(r4, (fvec4*)(outb + lin0));
}

extern "C" void kernel_launch(void* const* d_in, const int* in_sizes, int n_in,
                              void* d_out, int out_size, void* d_ws, size_t ws_size,
                              hipStream_t stream) {
    const float* image = (const float*)d_in[0];
    const float* ddf   = (const float*)d_in[1];
    float* out = (float*)d_out;

    warp_tile_kernel<<<B * 512, 1024, 0, stream>>>(image, ddf, out);
}

// Round 6
// 103.933 us; speedup vs baseline: 1.0705x; 1.0693x over previous
//
#include <hip/hip_runtime.h>
#include <hip/hip_fp16.h>

// Warp: trilinear grid_sample, padding_mode='zeros', align_corners=true.
// image: (B=2, C=1, H=128, W=128, D=128) fp32
// ddf:   (B=2, 3, H, W, D) fp32 voxel displacements; out: (B,1,H,W,D) fp32
//
// R17 = exact R14 restoration (best measured: 102.5us). Ledger of failed
// neighborhood moves, do NOT retry:
//  - R12 LDS 18-cell pad:       null (tap bank conflicts are hidden)
//  - R13 nontemporal ddf:       -14us (NT load hints bypass cache, regress)
//  - R15 rolling-x 2-tile:      -8.8us (fewer blocks + more barriers lose)
//  - R16 ddf after barrier:     -8.6us (pre-barrier ddf is concurrent with
//    staging loads -> barrier drain waits max(latency) not sum; post-barrier
//    it serializes at the head of compute)
// Structure: 1024 independent one-shot blocks (2/CU antiphase), XCD slab
// swizzle, fp32->fp16 LDS tile (64KB), 18-cell padded rows + v_alignbit
// (kept from R12: neutral), pre-barrier ddf, setprio(1) compute (T5, +2-3us).

constexpr int H = 128, W = 128, D = 128;
constexpr int N = H * W * D;      // 2^21
constexpr int B = 2;
constexpr int HA = 8;             // halo per side
constexpr int RS = 32;            // region edge
constexpr int RCELL = 18;         // padded cells (half2) per row (16 data + 2 pad)
constexpr int RHALF = RCELL * 2;  // halfs per row = 36
constexpr int RN = RS * RS * RHALF;  // 36864 halfs = 72 KB

typedef float fvec4 __attribute__((ext_vector_type(4)));
typedef unsigned u2v __attribute__((ext_vector_type(2), aligned(4)));
typedef unsigned u2v8 __attribute__((ext_vector_type(2), aligned(8)));

__global__ __launch_bounds__(1024, 8) void warp_tile_kernel(
    const float* __restrict__ image,
    const float* __restrict__ ddf,
    float* __restrict__ out)
{
    __shared__ __half tile[RN];   // 72 KB -> 2 blocks/CU

    // XCD slab swizzle: blocks dispatch round-robin over 8 XCDs; give XCD k
    // the contiguous tile range [k*128, (k+1)*128) (= 2 x-slabs, ~2MB image
    // region + halos -> fits that XCD's 4MB L2).
    int bid = blockIdx.x;
    int T   = (bid & 7) * 128 + (bid >> 3);
    int b  = T >> 9;              // 512 tiles per batch
    int t3 = T & 511;
    int tx0 = ((t3 >> 6) & 7) << 4;
    int ty0 = ((t3 >> 3) & 7) << 4;
    int tz0 = (t3 & 7) << 4;
    int ox = tx0 - HA, oy = ty0 - HA, oz = tz0 - HA;

    const float* img = image + ((size_t)b << 21);
    int t = threadIdx.x;          // 0..1023

    // ---- thread -> 4 consecutive z voxels ----
    int zq = (t & 3) << 2;        // 0,4,8,12
    int ly = (t >> 2) & 15;
    int lx = t >> 6;
    int vx = tx0 + lx, vy = ty0 + ly, vz = tz0 + zq;
    int lin0 = (vx << 14) + (vy << 7) + vz;      // 16B aligned

    // ---- stage 32^3 region as fp16 (zeros outside volume) ----
    // 4096 32-byte (8-float) chunks; chunk s: row = s>>2 (rx*32+ry),
    // zo = (s&3)*8. oz = 0 mod 8 -> chunk fully inside or fully outside.
    fvec4 sa[4], sb[4];
    int rows[4], zos[4];
#pragma unroll
    for (int c = 0; c < 4; ++c) {
        int s   = c * 1024 + t;
        int row = s >> 2;
        int zo  = (s & 3) << 3;
        rows[c] = row; zos[c] = zo;
        int gx = ox + (row >> 5);
        int gy = oy + (row & 31);
        int gz = oz + zo;
        bool ok = ((unsigned)gx < 128u) & ((unsigned)gy < 128u) & ((unsigned)gz < 121u);
        const float* p = img + (gx << 14) + (gy << 7) + gz;
        fvec4 z4 = {0.f, 0.f, 0.f, 0.f};
        sa[c] = ok ? *(const fvec4*)p       : z4;
        sb[c] = ok ? *(const fvec4*)(p + 4) : z4;
    }

    // ddf loads: issued pre-barrier, concurrent with the staging loads
    // (barrier drain waits on max latency, not sum -> effectively free).
    const float* ddfb = ddf + (size_t)b * 3 * N;
    fvec4 dx4 = *(const fvec4*)(ddfb + lin0);
    fvec4 dy4 = *(const fvec4*)(ddfb + lin0 + N);
    fvec4 dz4 = *(const fvec4*)(ddfb + lin0 + 2 * N);

    unsigned short* tp = (unsigned short*)tile;
#pragma unroll
    for (int c = 0; c < 4; ++c) {
        __half2 h0 = __floats2half2_rn(sa[c].x, sa[c].y);
        __half2 h1 = __floats2half2_rn(sa[c].z, sa[c].w);
        __half2 h2 = __floats2half2_rn(sb[c].x, sb[c].y);
        __half2 h3 = __floats2half2_rn(sb[c].z, sb[c].w);
        u2v8 w0, w1;
        w0.x = *(unsigned int*)&h0;
        w0.y = *(unsigned int*)&h1;
        w1.x = *(unsigned int*)&h2;
        w1.y = *(unsigned int*)&h3;
        // byte addr = 72*row + 2*zo + {0,8}: always 8B aligned -> ds_write_b64
        unsigned short* dst = tp + rows[c] * RHALF + zos[c];
        *(u2v8*)dst       = w0;
        *(u2v8*)(dst + 4) = w1;
    }
    __syncthreads();

    // Compute phase: boost issue priority. The co-resident block on this CU
    // is (typically) in its staging phase; preferring compute waves retires
    // blocks faster and smooths HBM demand (T5; independent-block regime).
    __builtin_amdgcn_s_setprio(1);

    // ---- compute 4 outputs (consecutive z), one float4 store ----
    float* outb = out + ((size_t)b << 21);
    const unsigned int* cells = (const unsigned int*)tile;   // half2 cells, 4B
    float dxp[4] = {dx4.x, dx4.y, dx4.z, dx4.w};
    float dyp[4] = {dy4.x, dy4.y, dy4.z, dy4.w};
    float dzp[4] = {dz4.x, dz4.y, dz4.z, dz4.w};
    float res[4];

#pragma unroll
    for (int i = 0; i < 4; ++i) {
        float x = (float)vx + dxp[i];
        float y = (float)vy + dyp[i];
        float z = (float)(vz + i) + dzp[i];

        float xf = floorf(x), yf = floorf(y), zf = floorf(z);
        float fx = x - xf, fy = y - yf, fz = z - zf;
        int x0 = (int)xf, y0 = (int)yf, z0 = (int)zf;
        int rx = x0 - ox, ry = y0 - oy, rz = z0 - oz;

        float acc;
        if ((unsigned)rx <= 30u && (unsigned)ry <= 30u && (unsigned)rz <= 30u) {
            // fast path: staged zeros implement zero-padding exactly.
            // z-pair (rz, rz+1) in cells c,c+1 (4B-aligned uint2 ->
            // ds_read2_b32; the straddle is resolved with v_alignbit).
            int row = (rx << 5) + ry;
            int c   = row * RCELL + (rz >> 1);
            int sh  = (rz & 1) << 4;
            u2v q00 = *(const u2v*)(cells + c);
            u2v q01 = *(const u2v*)(cells + c + RCELL);
            u2v q10 = *(const u2v*)(cells + c + 32 * RCELL);
            u2v q11 = *(const u2v*)(cells + c + 33 * RCELL);

            float az0 = 1.f - fz;
            float zz[4];
            unsigned los[4] = {q00.x, q01.x, q10.x, q11.x};
            unsigned his[4] = {q00.y, q01.y, q10.y, q11.y};
#pragma unroll
            for (int p2 = 0; p2 < 4; ++p2) {
                unsigned pr = __builtin_amdgcn_alignbit(his[p2], los[p2],
                                                        (unsigned)sh);
                __half2 hp = *(__half2*)&pr;
                float2 f2 = __half22float2(hp);
                zz[p2] = az0 * f2.x + fz * f2.y;
            }
            float ay0 = 1.f - fy;
            acc = (1.f - fx) * (ay0 * zz[0] + fy * zz[1]) +
                  fx         * (ay0 * zz[2] + fy * zz[3]);
        } else {
            // rare: exact fp32 global gather with zero-padding.
            int x1 = x0 + 1, y1 = y0 + 1, z1 = z0 + 1;
            bool vx0 = (unsigned)x0 < (unsigned)H;
            bool vx1 = (unsigned)x1 < (unsigned)H;
            bool vy0 = (unsigned)y0 < (unsigned)W;
            bool vy1 = (unsigned)y1 < (unsigned)W;
            bool vz0 = (unsigned)z0 < (unsigned)D;
            bool vz1 = (unsigned)z1 < (unsigned)D;
            float ax0 = vx0 ? (1.0f - fx) : 0.0f;
            float ax1 = vx1 ? fx          : 0.0f;
            float ay0 = vy0 ? (1.0f - fy) : 0.0f;
            float ay1 = vy1 ? fy          : 0.0f;
            float az0 = vz0 ? (1.0f - fz) : 0.0f;
            float az1 = vz1 ? fz          : 0.0f;
            int cx0 = vx0 ? x0 : 0;
            int cx1 = vx1 ? x1 : 0;
            int cy0 = vy0 ? y0 : 0;
            int cy1 = vy1 ? y1 : 0;
            int cz0 = vz0 ? z0 : 0;
            int cz1 = vz1 ? z1 : 0;
            int rx0 = cx0 << 14, rx1 = cx1 << 14;
            int ry0 = cy0 << 7,  ry1 = cy1 << 7;
            float v000 = img[rx0 + ry0 + cz0];
            float v001 = img[rx0 + ry0 + cz1];
            float v010 = img[rx0 + ry1 + cz0];
            float v011 = img[rx0 + ry1 + cz1];
            float v100 = img[rx1 + ry0 + cz0];
            float v101 = img[rx1 + ry0 + cz1];
            float v110 = img[rx1 + ry1 + cz0];
            float v111 = img[rx1 + ry1 + cz1];
            acc = ax0 * (ay0 * (az0 * v000 + az1 * v001) +
                         ay1 * (az0 * v010 + az1 * v011)) +
                  ax1 * (ay0 * (az0 * v100 + az1 * v101) +
                         ay1 * (az0 * v110 + az1 * v111));
        }
        res[i] = acc;
    }
    __builtin_amdgcn_s_setprio(0);
    fvec4 r4 = {res[0], res[1], res[2], res[3]};
    __builtin_nontemporal_store(r4, (fvec4*)(outb + lin0));
}

extern "C" void kernel_launch(void* const* d_in, const int* in_sizes, int n_in,
                              void* d_out, int out_size, void* d_ws, size_t ws_size,
                              hipStream_t stream) {
    const float* image = (const float*)d_in[0];
    const float* ddf   = (const float*)d_in[1];
    float* out = (float*)d_out;

    warp_tile_kernel<<<B * 512, 1024, 0, stream>>>(image, ddf, out);
}